// Round 8
// baseline (847.641 us; speedup 1.0000x reference)
//
#include <hip/hip_runtime.h>

typedef _Float16 f16;
typedef __attribute__((ext_vector_type(8))) _Float16 f16x8;
typedef __attribute__((ext_vector_type(4))) float f32x4;

#define BT   131072
#define DD   512
#define TM   16
#define MEFF 48
#define NBLK (BT / TM)  // 8192

// swizzled LDS fp16 tile: byte = row*1024 + (colbyte ^ ((row&7)<<4))
__device__ __forceinline__ void stA(char* ab, int row, int colbyte, float v) {
    *(f16*)(ab + row * 1024 + (colbyte ^ ((row & 7) << 4))) = (f16)v;
}
__device__ __forceinline__ f16x8 ldA8(const char* ab, int row, int kbyte) {
    return *(const f16x8*)(ab + row * 1024 + (kbyte ^ ((row & 7) << 4)));
}

__device__ __forceinline__ f16x8 cvt8(const float* q) {
    float4 u0 = *(const float4*)q;
    float4 u1 = *(const float4*)(q + 4);
    f16x8 r;
    r[0] = (f16)u0.x; r[1] = (f16)u0.y; r[2] = (f16)u0.z; r[3] = (f16)u0.w;
    r[4] = (f16)u1.x; r[5] = (f16)u1.y; r[6] = (f16)u1.z; r[7] = (f16)u1.w;
    return r;
}

// Pack W1..W3 (512x512 fp32 row-major) into MFMA B-fragment order fp16:
// frag f = (l*16+sk)*32 + nsub ; lane l: n = nsub*16+(lane&15), k = sk*32+(lane>>4)*8 .. +8
__global__ void prep_w(const float* __restrict__ W1, const float* __restrict__ W2,
                       const float* __restrict__ W3, f16* __restrict__ wp) {
    int tid = blockIdx.x * 256 + threadIdx.x;
    if (tid >= 3 * 16 * 32 * 64) return;
    int lane = tid & 63;
    int frag = tid >> 6;
    int nsub = frag & 31;
    int sk   = (frag >> 5) & 15;
    int l    = frag >> 9;
    const float* W = (l == 0) ? W1 : (l == 1) ? W2 : W3;
    int n = nsub * 16 + (lane & 15);
    int k = sk * 32 + (lane >> 4) * 8;
    ((f16x8*)wp)[tid] = cvt8(W + n * DD + k);
}

// 3 ds_read + 12 MFMA for one k-slice sk, B frags given as named regs.
#define MFMA_SK(skc, Q0, Q1, Q2, Q3)                                           \
    _Pragma("unroll")                                                          \
    for (int m = 0; m < 3; ++m) {                                              \
        f16x8 a = ldA8(ab, m * 16 + l15, (skc) * 64 + g16 * 16);               \
        acc[m][0] = __builtin_amdgcn_mfma_f32_16x16x32_f16(a, Q0, acc[m][0], 0, 0, 0); \
        acc[m][1] = __builtin_amdgcn_mfma_f32_16x16x32_f16(a, Q1, acc[m][1], 0, 0, 0); \
        acc[m][2] = __builtin_amdgcn_mfma_f32_16x16x32_f16(a, Q2, acc[m][2], 0, 0, 0); \
        acc[m][3] = __builtin_amdgcn_mfma_f32_16x16x32_f16(a, Q3, acc[m][3], 0, 0, 0); \
    }

#define LOADB(Q0, Q1, Q2, Q3, skc)                                             \
    if constexpr (PREP) {                                                      \
        const f16x8* p = wB + (size_t)((skc) * 32) * 64;                       \
        Q0 = p[0]; Q1 = p[64]; Q2 = p[128]; Q3 = p[192];                       \
    } else {                                                                   \
        const float* q = Wl + (size_t)(wv * 64 + l15) * DD + (skc) * 32 + g16 * 8; \
        Q0 = cvt8(q);                                                          \
        Q1 = cvt8(q + 16 * DD);                                                \
        Q2 = cvt8(q + 32 * DD);                                                \
        Q3 = cvt8(q + 48 * DD);                                                \
    }

template<bool PREP>
__global__ __launch_bounds__(512) void mlp_fused(
    const float* __restrict__ tx,
    const float* __restrict__ W0, const float* __restrict__ b0v,
    const float* __restrict__ W1, const float* __restrict__ b1v,
    const float* __restrict__ W2, const float* __restrict__ b2v,
    const float* __restrict__ W3, const float* __restrict__ b3v,
    const float* __restrict__ W4, const float* __restrict__ b4v,
    const f16* __restrict__ wp, float* __restrict__ out)
{
    // 48 KB A-tile -> 3 blocks/CU (144 KB of 160 KB), 6 waves/SIMD: the
    // round-7 lesson was that 1 block/CU (2 waves/SIMD) exposes every
    // dependency stall; cross-block overlap hides epilogue VALU under MFMA.
    __shared__ __align__(16) short abuf_s[MEFF * DD];  // 48 KB fp16, swizzled
    __shared__ float txb[TM * 3];
    char* ab = (char*)abuf_s;

    const int tid  = threadIdx.x;
    const int lane = tid & 63;
    const int wv   = tid >> 6;   // 0..7, owns cols [wv*64, wv*64+64)
    const int g16  = lane >> 4;
    const int l15  = lane & 15;
    const long s0  = (long)blockIdx.x * TM;

    if (tid < TM * 3) txb[tid] = tx[s0 * 3 + tid];
    __syncthreads();

    // ---- layer 0: z1 = W0 x + b0 (K=3, fp32 VALU); rows: h | sg*W0[:,1] | sg*W0[:,2]
    {
        int n = tid;
        float w0 = W0[n * 3 + 0], w1 = W0[n * 3 + 1], w2 = W0[n * 3 + 2], bb = b0v[n];
        #pragma unroll 4
        for (int s = 0; s < TM; ++s) {
            float z  = fmaf(w0, txb[s * 3], fmaf(w1, txb[s * 3 + 1], fmaf(w2, txb[s * 3 + 2], bb)));
            float aa = fabsf(z);
            float e  = __expf(-20.f * aa);
            float dd = 1.f + e;
            float h  = fmaxf(z, 0.f) + __logf(dd) * 0.05f;
            float sg = (z > 0.f ? 1.f : e) * __builtin_amdgcn_rcpf(dd);
            stA(ab, s,          n * 2, h);
            stA(ab, TM + s,     n * 2, sg * w1);
            stA(ab, 2 * TM + s, n * 2, sg * w2);
        }
    }
    __syncthreads();

    // ---- layers 1..3: fused GEMM over M_eff=48 rows (h + 2 tangents), N=K=512
    // Arch-VGPR discipline (rounds 1-6): named B regs only, no lambdas,
    // compile-time acc indices, sk-loop unroll 2, B double-buffered in named regs.
    for (int l = 0; l < 3; ++l) {
        const float* Wl = (l == 0) ? W1 : (l == 1) ? W2 : W3;
        const float* bl = (l == 0) ? b1v : (l == 1) ? b2v : b3v;
        const f16x8* wB = (const f16x8*)wp + (size_t)l * (16 * 32 * 64)
                        + (size_t)(wv * 4) * 64 + lane;

        f32x4 acc[3][4];
        #pragma unroll
        for (int m = 0; m < 3; ++m)
            #pragma unroll
            for (int n = 0; n < 4; ++n)
                acc[m][n] = f32x4{0.f, 0.f, 0.f, 0.f};

        f16x8 B0, B1, B2, B3, C0, C1, C2, C3;
        LOADB(B0, B1, B2, B3, 0)
        #pragma unroll 2
        for (int sk = 0; sk < 16; sk += 2) {
            LOADB(C0, C1, C2, C3, sk + 1)
            MFMA_SK(sk, B0, B1, B2, B3)
            if (sk + 2 < 16) { LOADB(B0, B1, B2, B3, sk + 2) }
            MFMA_SK(sk + 1, C0, C1, C2, C3)
        }

        __syncthreads();  // all waves done reading abuf

        // fused epilogue: per element compute h,sigma inline and write all
        // three rows (h, sg*xdot, sg*ydot). No sigma register array.
        #pragma unroll
        for (int n = 0; n < 4; ++n) {
            float bias = bl[wv * 64 + n * 16 + l15];
            int   cb   = (wv * 64 + n * 16 + l15) * 2;
            #pragma unroll
            for (int r = 0; r < 4; ++r) {
                int row = g16 * 4 + r;
                float z  = acc[0][n][r] + bias;
                float aa = fabsf(z);
                float e  = __expf(-20.f * aa);
                float dd = 1.f + e;
                float h  = fmaxf(z, 0.f) + __logf(dd) * 0.05f;
                float sg = (z > 0.f ? 1.f : e) * __builtin_amdgcn_rcpf(dd);
                stA(ab, row,      cb, h);
                stA(ab, row + 16, cb, sg * acc[1][n][r]);
                stA(ab, row + 32, cb, sg * acc[2][n][r]);
            }
        }
        __syncthreads();
    }

    // ---- final layer (fp32 VALU dots): p = W4[1].h4 + b4[1]; u = (ds/dy, -ds/dx)
    {
        const int kb = lane * 8;
        float wsr[8], wpr[8];
        #pragma unroll
        for (int j = 0; j < 8; ++j) { wsr[j] = W4[kb + j]; wpr[j] = W4[DD + kb + j]; }
        float bp = b4v[1];
        #pragma unroll
        for (int i = 0; i < 2; ++i) {
            int s = wv * 2 + i;
            f16x8 hh = ldA8(ab, s,      lane * 16);
            f16x8 hx = ldA8(ab, 16 + s, lane * 16);
            f16x8 hy = ldA8(ab, 32 + s, lane * 16);
            float dy = 0.f, dx = 0.f, dp = 0.f;
            #pragma unroll
            for (int j = 0; j < 8; ++j) {
                dy = fmaf(wsr[j], (float)hy[j], dy);
                dx = fmaf(wsr[j], (float)hx[j], dx);
                dp = fmaf(wpr[j], (float)hh[j], dp);
            }
            #pragma unroll
            for (int mk = 1; mk < 64; mk <<= 1) {
                dy += __shfl_xor(dy, mk);
                dx += __shfl_xor(dx, mk);
                dp += __shfl_xor(dp, mk);
            }
            if (lane == 0) {
                float* o = out + (s0 + s) * 3;
                o[0] = dy;        // ds/dy
                o[1] = -dx;       // -ds/dx
                o[2] = dp + bp;   // pressure
            }
        }
    }
}

extern "C" void kernel_launch(void* const* d_in, const int* in_sizes, int n_in,
                              void* d_out, int out_size, void* d_ws, size_t ws_size,
                              hipStream_t stream) {
    const float* tx = (const float*)d_in[0];
    const float* W0 = (const float*)d_in[1]; const float* b0 = (const float*)d_in[2];
    const float* W1 = (const float*)d_in[3]; const float* b1 = (const float*)d_in[4];
    const float* W2 = (const float*)d_in[5]; const float* b2 = (const float*)d_in[6];
    const float* W3 = (const float*)d_in[7]; const float* b3 = (const float*)d_in[8];
    const float* W4 = (const float*)d_in[9]; const float* b4 = (const float*)d_in[10];
    float* out = (float*)d_out;

    const size_t need = (size_t)3 * 512 * 512 * sizeof(f16);
    if (ws_size >= need) {
        f16* wp = (f16*)d_ws;
        prep_w<<<(3 * 16 * 32 * 64 + 255) / 256, 256, 0, stream>>>(W1, W2, W3, wp);
        mlp_fused<true><<<NBLK, 512, 0, stream>>>(tx, W0, b0, W1, b1, W2, b2, W3, b3, W4, b4, wp, out);
    } else {
        mlp_fused<false><<<NBLK, 512, 0, stream>>>(tx, W0, b0, W1, b1, W2, b2, W3, b3, W4, b4, nullptr, out);
    }
}

// Round 9
// 792.911 us; speedup vs baseline: 1.0690x; 1.0690x over previous
//
#include <hip/hip_runtime.h>

typedef _Float16 f16;
typedef __attribute__((ext_vector_type(8))) _Float16 f16x8;
typedef __attribute__((ext_vector_type(4))) float f32x4;

#define BT   131072
#define DD   512
#define TM   32
#define MEFF 96
#define NBLK (BT / TM)  // 4096

// swizzled LDS fp16 tile: byte = row*1024 + (colbyte ^ ((row&7)<<4))
__device__ __forceinline__ void stA(char* ab, int row, int colbyte, float v) {
    *(f16*)(ab + row * 1024 + (colbyte ^ ((row & 7) << 4))) = (f16)v;
}
__device__ __forceinline__ f16x8 ldA8(const char* ab, int row, int kbyte) {
    return *(const f16x8*)(ab + row * 1024 + (kbyte ^ ((row & 7) << 4)));
}

__device__ __forceinline__ f16x8 cvt8(const float* q) {
    float4 u0 = *(const float4*)q;
    float4 u1 = *(const float4*)(q + 4);
    f16x8 r;
    r[0] = (f16)u0.x; r[1] = (f16)u0.y; r[2] = (f16)u0.z; r[3] = (f16)u0.w;
    r[4] = (f16)u1.x; r[5] = (f16)u1.y; r[6] = (f16)u1.z; r[7] = (f16)u1.w;
    return r;
}

// acquire-spin until *p >= v (LDS flag, workgroup scope; uniform across wave)
__device__ __forceinline__ void waitge(int* p, int v) {
    if (__hip_atomic_load(p, __ATOMIC_ACQUIRE, __HIP_MEMORY_SCOPE_WORKGROUP) >= v) return;
    while (__hip_atomic_load(p, __ATOMIC_ACQUIRE, __HIP_MEMORY_SCOPE_WORKGROUP) < v)
        __builtin_amdgcn_s_sleep(1);
}
// release-store (drains this wave's prior LDS reads/writes first)
__device__ __forceinline__ void st_rel(int* p, int v) {
    __hip_atomic_store(p, v, __ATOMIC_RELEASE, __HIP_MEMORY_SCOPE_WORKGROUP);
}

// Pack W1..W3 (512x512 fp32 row-major) into MFMA B-fragment order fp16:
// frag f = (l*16+sk)*32 + nsub ; lane l: n = nsub*16+(lane&15), k = sk*32+(lane>>4)*8 .. +8
__global__ void prep_w(const float* __restrict__ W1, const float* __restrict__ W2,
                       const float* __restrict__ W3, f16* __restrict__ wp) {
    int tid = blockIdx.x * 256 + threadIdx.x;
    if (tid >= 3 * 16 * 32 * 64) return;
    int lane = tid & 63;
    int frag = tid >> 6;
    int nsub = frag & 31;
    int sk   = (frag >> 5) & 15;
    int l    = frag >> 9;
    const float* W = (l == 0) ? W1 : (l == 1) ? W2 : W3;
    int n = nsub * 16 + (lane & 15);
    int k = sk * 32 + (lane >> 4) * 8;
    ((f16x8*)wp)[tid] = cvt8(W + n * DD + k);
}

// 6 ds_read + 24 MFMA for one k-chunk c, B frags as named regs.
#define MFMA_SK(cc, Q0, Q1, Q2, Q3)                                            \
    _Pragma("unroll")                                                          \
    for (int m = 0; m < 6; ++m) {                                              \
        f16x8 a = ldA8(ab, m * 16 + l15, (cc) * 64 + g16 * 16);                \
        acc[m][0] = __builtin_amdgcn_mfma_f32_16x16x32_f16(a, Q0, acc[m][0], 0, 0, 0); \
        acc[m][1] = __builtin_amdgcn_mfma_f32_16x16x32_f16(a, Q1, acc[m][1], 0, 0, 0); \
        acc[m][2] = __builtin_amdgcn_mfma_f32_16x16x32_f16(a, Q2, acc[m][2], 0, 0, 0); \
        acc[m][3] = __builtin_amdgcn_mfma_f32_16x16x32_f16(a, Q3, acc[m][3], 0, 0, 0); \
    }

#define LOADB(Q0, Q1, Q2, Q3, cc)                                              \
    if constexpr (PREP) {                                                      \
        const f16x8* p = wB + ((size_t)(cc) << 11);                            \
        Q0 = p[0]; Q1 = p[64]; Q2 = p[128]; Q3 = p[192];                       \
    } else {                                                                   \
        const float* q = Wl + (size_t)(wv * 64 + l15) * DD + (cc) * 32 + g16 * 8; \
        Q0 = cvt8(q);                                                          \
        Q1 = cvt8(q + 16 * DD);                                                \
        Q2 = cvt8(q + 32 * DD);                                                \
        Q3 = cvt8(q + 48 * DD);                                                \
    }

template<bool PREP>
__global__ __launch_bounds__(512) void mlp_fused(
    const float* __restrict__ tx,
    const float* __restrict__ W0, const float* __restrict__ b0v,
    const float* __restrict__ W1, const float* __restrict__ b1v,
    const float* __restrict__ W2, const float* __restrict__ b2v,
    const float* __restrict__ W3, const float* __restrict__ b3v,
    const float* __restrict__ W4, const float* __restrict__ b4v,
    const f16* __restrict__ wp, float* __restrict__ out)
{
    // Barrier-free layer pipeline (round-9): per-chunk ready[] generations +
    // per-wave progress[] gate the in-place A-tile. Waves drift, so one
    // wave's epilogue VALU overlaps the other SIMD-wave's MFMA k-loop.
    __shared__ __align__(16) short abuf_s[MEFF * DD];  // 96 KB fp16, swizzled
    __shared__ float txb[TM * 3];
    __shared__ int ready[16];    // chunk c readable at generation ready[c] (1=L0 out, li+2=epi li out)
    __shared__ int progress[8];  // k-loops completed per wave
    char* ab = (char*)abuf_s;

    const int tid  = threadIdx.x;
    const int lane = tid & 63;
    const int wv   = tid >> 6;   // 0..7, owns cols [wv*64, wv*64+64) = chunks 2wv, 2wv+1
    const int g16  = lane >> 4;
    const int l15  = lane & 15;
    const long s0  = (long)blockIdx.x * TM;

    if (tid < 16) ready[tid] = 0;
    if (tid >= 16 && tid < 24) progress[tid - 16] = 0;
    if (tid < TM * 3) txb[tid] = tx[s0 * 3 + tid];
    __syncthreads();  // txb + flag init visible (only barrier in the kernel)

    // ---- layer 0: z1 = W0 x + b0 (K=3, fp32 VALU); rows: h | sg*W0[:,1] | sg*W0[:,2]
    {
        int n = tid;
        float w0 = W0[n * 3 + 0], w1 = W0[n * 3 + 1], w2 = W0[n * 3 + 2], bb = b0v[n];
        #pragma unroll 4
        for (int s = 0; s < TM; ++s) {
            float z  = fmaf(w0, txb[s * 3], fmaf(w1, txb[s * 3 + 1], fmaf(w2, txb[s * 3 + 2], bb)));
            float aa = fabsf(z);
            float e  = __expf(-20.f * aa);
            float dd = 1.f + e;
            float h  = fmaxf(z, 0.f) + __logf(dd) * 0.05f;
            float sg = (z > 0.f ? 1.f : e) * __builtin_amdgcn_rcpf(dd);
            stA(ab, s,          n * 2, h);
            stA(ab, TM + s,     n * 2, sg * w1);
            stA(ab, 2 * TM + s, n * 2, sg * w2);
        }
    }
    if (lane == 0) { st_rel(&ready[2 * wv], 1); st_rel(&ready[2 * wv + 1], 1); }

    // ---- layers 1..3: fused GEMM over M_eff=96 rows (h + 2 tangents), N=K=512
    // Arch-VGPR discipline (rounds 1-6): named B regs, no lambdas, unroll 2,
    // single-buffered B (round 7: dbuf was neutral; frees regs for flag logic).
    for (int li = 0; li < 3; ++li) {
        const float* Wl = (li == 0) ? W1 : (li == 1) ? W2 : W3;
        const float* bl = (li == 0) ? b1v : (li == 1) ? b2v : b3v;
        const f16x8* wB = (const f16x8*)wp + (size_t)li * (16 * 32 * 64)
                        + (size_t)(wv * 4) * 64 + lane;

        f32x4 acc[6][4];
        #pragma unroll
        for (int m = 0; m < 6; ++m)
            #pragma unroll
            for (int n = 0; n < 4; ++n)
                acc[m][n] = f32x4{0.f, 0.f, 0.f, 0.f};

        // rotated consumption: start at own chunks (ready immediately after
        // this wave's own epilogue) then sweep neighbors as they publish.
        int c = 2 * wv;
        #pragma unroll 2
        for (int j = 0; j < 16; ++j) {
            f16x8 b0, b1, b2, b3;
            LOADB(b0, b1, b2, b3, c)      // global W stream: not flag-gated
            waitge(&ready[c], li + 1);    // A-chunk generation gate
            MFMA_SK(c, b0, b1, b2, b3)
            c = (c + 1) & 15;
        }
        if (lane == 0) st_rel(&progress[wv], li + 1);  // lgkm-drained: my reads retired

        // in-place overwrite gate: every wave finished reading generation li+1
        #pragma unroll 1
        for (int w = 0; w < 8; ++w) waitge(&progress[w], li + 1);

        // fused epilogue: h,sigma inline; write h + both scaled tangent rows.
        #pragma unroll
        for (int m = 0; m < 2; ++m)
            #pragma unroll
            for (int n = 0; n < 4; ++n) {
                float bias = bl[wv * 64 + n * 16 + l15];
                int   cb   = (wv * 64 + n * 16 + l15) * 2;
                #pragma unroll
                for (int r = 0; r < 4; ++r) {
                    int row = m * 16 + g16 * 4 + r;
                    float z  = acc[m][n][r] + bias;
                    float aa = fabsf(z);
                    float e  = __expf(-20.f * aa);
                    float dd = 1.f + e;
                    float h  = fmaxf(z, 0.f) + __logf(dd) * 0.05f;
                    float sg = (z > 0.f ? 1.f : e) * __builtin_amdgcn_rcpf(dd);
                    stA(ab, row,      cb, h);
                    stA(ab, row + 32, cb, sg * acc[m + 2][n][r]);
                    stA(ab, row + 64, cb, sg * acc[m + 4][n][r]);
                }
            }
        if (lane == 0) { st_rel(&ready[2 * wv], li + 2); st_rel(&ready[2 * wv + 1], li + 2); }
    }

    // ---- final layer: wait all chunks at generation 4, then fp32 VALU dots
    #pragma unroll 1
    for (int cc = 0; cc < 16; ++cc) waitge(&ready[cc], 4);
    {
        const int kb = lane * 8;
        float wsr[8], wpr[8];
        #pragma unroll
        for (int j = 0; j < 8; ++j) { wsr[j] = W4[kb + j]; wpr[j] = W4[DD + kb + j]; }
        float bp = b4v[1];
        #pragma unroll
        for (int i = 0; i < 4; ++i) {
            int s = wv * 4 + i;
            f16x8 hh = ldA8(ab, s,      lane * 16);
            f16x8 hx = ldA8(ab, 32 + s, lane * 16);
            f16x8 hy = ldA8(ab, 64 + s, lane * 16);
            float dy = 0.f, dx = 0.f, dp = 0.f;
            #pragma unroll
            for (int j = 0; j < 8; ++j) {
                dy = fmaf(wsr[j], (float)hy[j], dy);
                dx = fmaf(wsr[j], (float)hx[j], dx);
                dp = fmaf(wpr[j], (float)hh[j], dp);
            }
            #pragma unroll
            for (int mk = 1; mk < 64; mk <<= 1) {
                dy += __shfl_xor(dy, mk);
                dx += __shfl_xor(dx, mk);
                dp += __shfl_xor(dp, mk);
            }
            if (lane == 0) {
                float* o = out + (s0 + s) * 3;
                o[0] = dy;        // ds/dy
                o[1] = -dx;       // -ds/dx
                o[2] = dp + bp;   // pressure
            }
        }
    }
}

extern "C" void kernel_launch(void* const* d_in, const int* in_sizes, int n_in,
                              void* d_out, int out_size, void* d_ws, size_t ws_size,
                              hipStream_t stream) {
    const float* tx = (const float*)d_in[0];
    const float* W0 = (const float*)d_in[1]; const float* b0 = (const float*)d_in[2];
    const float* W1 = (const float*)d_in[3]; const float* b1 = (const float*)d_in[4];
    const float* W2 = (const float*)d_in[5]; const float* b2 = (const float*)d_in[6];
    const float* W3 = (const float*)d_in[7]; const float* b3 = (const float*)d_in[8];
    const float* W4 = (const float*)d_in[9]; const float* b4 = (const float*)d_in[10];
    float* out = (float*)d_out;

    const size_t need = (size_t)3 * 512 * 512 * sizeof(f16);
    if (ws_size >= need) {
        f16* wp = (f16*)d_ws;
        prep_w<<<(3 * 16 * 32 * 64 + 255) / 256, 256, 0, stream>>>(W1, W2, W3, wp);
        mlp_fused<true><<<NBLK, 512, 0, stream>>>(tx, W0, b0, W1, b1, W2, b2, W3, b3, W4, b4, wp, out);
    } else {
        mlp_fused<false><<<NBLK, 512, 0, stream>>>(tx, W0, b0, W1, b1, W2, b2, W3, b3, W4, b4, nullptr, out);
    }
}

// Round 10
// 776.303 us; speedup vs baseline: 1.0919x; 1.0214x over previous
//
#include <hip/hip_runtime.h>

typedef _Float16 f16;
typedef __attribute__((ext_vector_type(8))) _Float16 f16x8;
typedef __attribute__((ext_vector_type(4))) float f32x4;

#define BT   131072
#define DD   512
#define TM   32
#define NBLK (BT / TM)  // 4096

// swizzled LDS fp16 tile (rows 0..31 per 32KB tile):
// byte = row*1024 + (colbyte ^ ((row&7)<<4))
__device__ __forceinline__ void stA(char* tb, int row, int colbyte, float v) {
    *(f16*)(tb + row * 1024 + (colbyte ^ ((row & 7) << 4))) = (f16)v;
}
__device__ __forceinline__ f16x8 ldA8(const char* tb, int row, int kbyte) {
    return *(const f16x8*)(tb + row * 1024 + (kbyte ^ ((row & 7) << 4)));
}
__device__ __forceinline__ float ldh(const char* tb, int row, int colbyte) {
    return (float)*(const f16*)(tb + row * 1024 + (colbyte ^ ((row & 7) << 4)));
}

__device__ __forceinline__ f16x8 cvt8(const float* q) {
    float4 u0 = *(const float4*)q;
    float4 u1 = *(const float4*)(q + 4);
    f16x8 r;
    r[0] = (f16)u0.x; r[1] = (f16)u0.y; r[2] = (f16)u0.z; r[3] = (f16)u0.w;
    r[4] = (f16)u1.x; r[5] = (f16)u1.y; r[6] = (f16)u1.z; r[7] = (f16)u1.w;
    return r;
}

// Pack 6 sections of B-fragments (each 16sk x 32nsub x 64lane f16x8):
// sections 0..2: forward W1..W3  (N=out row n, K=in k):  elem W[n*DD + k+j]
// sections 3..5: backward W1..W3 transposed (K=out, N=in): elem W[(k+j)*DD + n]
__global__ void prep_w(const float* __restrict__ W1, const float* __restrict__ W2,
                       const float* __restrict__ W3, f16* __restrict__ wp) {
    int tid = blockIdx.x * 256 + threadIdx.x;
    if (tid >= 6 * 16 * 32 * 64) return;
    int lane = tid & 63;
    int frag = tid >> 6;
    int nsub = frag & 31;
    int sk   = (frag >> 5) & 15;
    int l    = frag >> 9;          // 0..5
    int lw   = l - (l >= 3 ? 3 : 0);
    const float* W = (lw == 0) ? W1 : (lw == 1) ? W2 : W3;
    int n = nsub * 16 + (lane & 15);
    int k = sk * 32 + (lane >> 4) * 8;
    f16x8 o;
    if (l < 3) {
        const float* p = W + (size_t)n * DD + k;
        #pragma unroll
        for (int j = 0; j < 8; ++j) o[j] = (f16)p[j];
    } else {
        const float* p = W + (size_t)k * DD + n;
        #pragma unroll
        for (int j = 0; j < 8; ++j) o[j] = (f16)p[j * DD];
    }
    ((f16x8*)wp)[tid] = o;
}

#define MFMA1(A, B, C) __builtin_amdgcn_mfma_f32_16x16x32_f16(A, B, C, 0, 0, 0)

// one k-slice: 2 A-rows (M=32) x 4 B frags -> 8 MFMA
#define MFMA_SK2(TB, skc, Q0, Q1, Q2, Q3)                                      \
    { f16x8 aA = ldA8(TB, l15,      (skc) * 64 + g16 * 16);                    \
      f16x8 aB = ldA8(TB, 16 + l15, (skc) * 64 + g16 * 16);                    \
      acc[0][0] = MFMA1(aA, Q0, acc[0][0]); acc[0][1] = MFMA1(aA, Q1, acc[0][1]); \
      acc[0][2] = MFMA1(aA, Q2, acc[0][2]); acc[0][3] = MFMA1(aA, Q3, acc[0][3]); \
      acc[1][0] = MFMA1(aB, Q0, acc[1][0]); acc[1][1] = MFMA1(aB, Q1, acc[1][1]); \
      acc[1][2] = MFMA1(aB, Q2, acc[1][2]); acc[1][3] = MFMA1(aB, Q3, acc[1][3]); }

// packed B load (PREP) for section pointer wS (pre-offset by wave+lane)
#define LOADB_P(wS, Q0, Q1, Q2, Q3, skc)                                       \
    { const f16x8* p_ = (wS) + ((size_t)(skc) << 11);                          \
      Q0 = p_[0]; Q1 = p_[64]; Q2 = p_[128]; Q3 = p_[192]; }

template<bool PREP>
__global__ __launch_bounds__(512) void mlp_fused(
    const float* __restrict__ tx,
    const float* __restrict__ W0, const float* __restrict__ b0v,
    const float* __restrict__ W1, const float* __restrict__ b1v,
    const float* __restrict__ W2, const float* __restrict__ b2v,
    const float* __restrict__ W3, const float* __restrict__ b3v,
    const float* __restrict__ W4, const float* __restrict__ b4v,
    const f16* __restrict__ wp, float* __restrict__ out)
{
    // Reverse-mode: forward stores h1,h2,h3 (tiles 0..2); g-tile holds the
    // backward vector gz_l. 1.5x fewer MFMA than forward-tangent mode.
    __shared__ __align__(16) short abuf_s[4 * 32 * DD];  // 128 KB
    __shared__ float txb[TM * 3];
    __shared__ float pbuf[8][32];                        // p partials per wave
    char* ab = (char*)abuf_s;
    char* G  = ab + 3 * 32768;

    const int tid  = threadIdx.x;
    const int lane = tid & 63;
    const int wv   = tid >> 6;   // 0..7, owns cols [wv*64, wv*64+64)
    const int g16  = lane >> 4;
    const int l15  = lane & 15;
    const long s0  = (long)blockIdx.x * TM;

    if (tid < TM * 3) txb[tid] = tx[s0 * 3 + tid];
    __syncthreads();

    // ---- layer 0: h1 = sp20(W0 x + b0)  (K=3, fp32 VALU) -> tile 0
    {
        int n = tid;
        float w0 = W0[n * 3 + 0], w1 = W0[n * 3 + 1], w2 = W0[n * 3 + 2], bb = b0v[n];
        #pragma unroll 4
        for (int s = 0; s < TM; ++s) {
            float z  = fmaf(w0, txb[s * 3], fmaf(w1, txb[s * 3 + 1], fmaf(w2, txb[s * 3 + 2], bb)));
            float aa = fabsf(z);
            float e  = __expf(-20.f * aa);
            float dd = 1.f + e;
            float h  = fmaxf(z, 0.f) + __logf(dd) * 0.05f;
            stA(ab, s, n * 2, h);
        }
    }
    __syncthreads();

    // ---- forward: h_{i+2} = sp20(W_{i+1} h_{i+1} + b)  (i=0,1); i=2 -> gz4 + p
    for (int i = 0; i < 3; ++i) {
        const float* Wl = (i == 0) ? W1 : (i == 1) ? W2 : W3;
        const float* bl = (i == 0) ? b1v : (i == 1) ? b2v : b3v;
        const f16x8* wS = (const f16x8*)wp + (size_t)i * (16 * 32 * 64)
                        + (size_t)(wv * 4) * 64 + lane;
        const char* Tin = ab + i * 32768;

        f32x4 acc[2][4];
        #pragma unroll
        for (int m = 0; m < 2; ++m)
            #pragma unroll
            for (int n = 0; n < 4; ++n)
                acc[m][n] = f32x4{0.f, 0.f, 0.f, 0.f};

        #pragma unroll 2
        for (int sk = 0; sk < 16; ++sk) {
            f16x8 b0, b1, b2, b3;
            if constexpr (PREP) {
                LOADB_P(wS, b0, b1, b2, b3, sk)
            } else {
                const float* q = Wl + (size_t)(wv * 64 + l15) * DD + sk * 32 + g16 * 8;
                b0 = cvt8(q);
                b1 = cvt8(q + 16 * DD);
                b2 = cvt8(q + 32 * DD);
                b3 = cvt8(q + 48 * DD);
            }
            MFMA_SK2(Tin, sk, b0, b1, b2, b3)
        }

        if (i < 2) {
            char* Tout = ab + (i + 1) * 32768;
            #pragma unroll
            for (int m = 0; m < 2; ++m)
                #pragma unroll
                for (int n = 0; n < 4; ++n) {
                    float bias = bl[wv * 64 + n * 16 + l15];
                    int   cb   = (wv * 64 + n * 16 + l15) * 2;
                    #pragma unroll
                    for (int r = 0; r < 4; ++r) {
                        int row = m * 16 + g16 * 4 + r;
                        float z  = acc[m][n][r] + bias;
                        float aa = fabsf(z);
                        float e  = __expf(-20.f * aa);
                        float dd = 1.f + e;
                        float h  = fmaxf(z, 0.f) + __logf(dd) * 0.05f;
                        stA(Tout, row, cb, h);
                    }
                }
        } else {
            // z4 -> gz4 = W4[0][col]*sigmoid(20 z4) -> G ; p-partials -> pbuf
            #pragma unroll
            for (int m = 0; m < 2; ++m)
                #pragma unroll
                for (int r = 0; r < 4; ++r) {
                    int row = m * 16 + g16 * 4 + r;
                    float pp = 0.f;
                    #pragma unroll
                    for (int n = 0; n < 4; ++n) {
                        int col = wv * 64 + n * 16 + l15;
                        float z  = acc[m][n][r] + bl[col];
                        float aa = fabsf(z);
                        float e  = __expf(-20.f * aa);
                        float dd = 1.f + e;
                        float rd = __builtin_amdgcn_rcpf(dd);
                        float h4 = fmaxf(z, 0.f) + __logf(dd) * 0.05f;
                        float sg = (z > 0.f ? 1.f : e) * rd;
                        pp = fmaf(W4[DD + col], h4, pp);
                        stA(G, row, col * 2, W4[col] * sg);
                    }
                    pp += __shfl_xor(pp, 1);
                    pp += __shfl_xor(pp, 2);
                    pp += __shfl_xor(pp, 4);
                    pp += __shfl_xor(pp, 8);
                    if (l15 == 0) pbuf[wv][row] = pp;
                }
        }
        __syncthreads();
    }

    // ---- backward: gz_{3-b} = (gz_{4-b} W_{3-b}^T) * sigma(h_{3-b}), in-place in G
    for (int b = 0; b < 3; ++b) {
        const f16x8* wS = (const f16x8*)wp + (size_t)(5 - b) * (16 * 32 * 64)
                        + (size_t)(wv * 4) * 64 + lane;
        const float* Wb = (b == 0) ? W3 : (b == 1) ? W2 : W1;
        const char* Th = ab + (2 - b) * 32768;  // h_{3-b}

        f32x4 acc[2][4];
        #pragma unroll
        for (int m = 0; m < 2; ++m)
            #pragma unroll
            for (int n = 0; n < 4; ++n)
                acc[m][n] = f32x4{0.f, 0.f, 0.f, 0.f};

        #pragma unroll 2
        for (int sk = 0; sk < 16; ++sk) {
            f16x8 b0, b1, b2, b3;
            if constexpr (PREP) {
                LOADB_P(wS, b0, b1, b2, b3, sk)
            } else {
                const float* q = Wb + (size_t)(sk * 32 + g16 * 8) * DD + wv * 64 + l15;
                f16x8 t0, t1, t2, t3;
                #pragma unroll
                for (int j = 0; j < 8; ++j) {
                    t0[j] = (f16)q[j * DD];
                    t1[j] = (f16)q[j * DD + 16];
                    t2[j] = (f16)q[j * DD + 32];
                    t3[j] = (f16)q[j * DD + 48];
                }
                b0 = t0; b1 = t1; b2 = t2; b3 = t3;
            }
            MFMA_SK2(G, sk, b0, b1, b2, b3)
        }
        __syncthreads();  // all waves done reading G before overwrite

        #pragma unroll
        for (int m = 0; m < 2; ++m)
            #pragma unroll
            for (int n = 0; n < 4; ++n) {
                int cb = (wv * 64 + n * 16 + l15) * 2;
                #pragma unroll
                for (int r = 0; r < 4; ++r) {
                    int row = m * 16 + g16 * 4 + r;
                    float h  = ldh(Th, row, cb);
                    float sg = 1.f - __expf(-20.f * h);  // sigmoid(20z) via h
                    stA(G, row, cb, sg * acc[m][n][r]);
                }
            }
        __syncthreads();
    }

    // ---- final: u = (dy, -dx) from gz1 . W0 cols; p from pbuf
    {
        const int kb = lane * 8;
        float wyr[8], wxr[8];
        #pragma unroll
        for (int j = 0; j < 8; ++j) {
            wyr[j] = W0[(kb + j) * 3 + 2];
            wxr[j] = W0[(kb + j) * 3 + 1];
        }
        float bp = b4v[1];
        #pragma unroll
        for (int ii = 0; ii < 4; ++ii) {
            int s = wv * 4 + ii;
            f16x8 gg = ldA8(G, s, lane * 16);
            float dy = 0.f, dx = 0.f;
            #pragma unroll
            for (int j = 0; j < 8; ++j) {
                dy = fmaf(wyr[j], (float)gg[j], dy);
                dx = fmaf(wxr[j], (float)gg[j], dx);
            }
            #pragma unroll
            for (int mk = 1; mk < 64; mk <<= 1) {
                dy += __shfl_xor(dy, mk);
                dx += __shfl_xor(dx, mk);
            }
            if (lane == 0) {
                float ps = bp;
                #pragma unroll
                for (int w = 0; w < 8; ++w) ps += pbuf[w][s];
                float* o = out + (s0 + s) * 3;
                o[0] = dy;        // ds/dy
                o[1] = -dx;       // -ds/dx
                o[2] = ps;        // pressure
            }
        }
    }
}

extern "C" void kernel_launch(void* const* d_in, const int* in_sizes, int n_in,
                              void* d_out, int out_size, void* d_ws, size_t ws_size,
                              hipStream_t stream) {
    const float* tx = (const float*)d_in[0];
    const float* W0 = (const float*)d_in[1]; const float* b0 = (const float*)d_in[2];
    const float* W1 = (const float*)d_in[3]; const float* b1 = (const float*)d_in[4];
    const float* W2 = (const float*)d_in[5]; const float* b2 = (const float*)d_in[6];
    const float* W3 = (const float*)d_in[7]; const float* b3 = (const float*)d_in[8];
    const float* W4 = (const float*)d_in[9]; const float* b4 = (const float*)d_in[10];
    float* out = (float*)d_out;

    const size_t need = (size_t)6 * 512 * 512 * sizeof(f16);  // 3 MB: fwd + bwd packs
    if (ws_size >= need) {
        f16* wp = (f16*)d_ws;
        prep_w<<<(6 * 16 * 32 * 64 + 255) / 256, 256, 0, stream>>>(W1, W2, W3, wp);
        mlp_fused<true><<<NBLK, 512, 0, stream>>>(tx, W0, b0, W1, b1, W2, b2, W3, b3, W4, b4, wp, out);
    } else {
        mlp_fused<false><<<NBLK, 512, 0, stream>>>(tx, W0, b0, W1, b1, W2, b2, W3, b3, W4, b4, nullptr, out);
    }
}

// Round 11
// 754.266 us; speedup vs baseline: 1.1238x; 1.0292x over previous
//
#include <hip/hip_runtime.h>

typedef _Float16 f16;
typedef __attribute__((ext_vector_type(8))) _Float16 f16x8;
typedef __attribute__((ext_vector_type(4))) float f32x4;

#define BT   131072
#define DD   512
#define TM   32
#define NBLK (BT / TM)  // 4096

// swizzled LDS fp16 tile (rows 0..31 per 32KB tile):
// byte = row*1024 + (colbyte ^ ((row&7)<<4))
__device__ __forceinline__ void stA(char* tb, int row, int colbyte, float v) {
    *(f16*)(tb + row * 1024 + (colbyte ^ ((row & 7) << 4))) = (f16)v;
}
__device__ __forceinline__ f16x8 ldA8(const char* tb, int row, int kbyte) {
    return *(const f16x8*)(tb + row * 1024 + (kbyte ^ ((row & 7) << 4)));
}
__device__ __forceinline__ float ldh(const char* tb, int row, int colbyte) {
    return (float)*(const f16*)(tb + row * 1024 + (colbyte ^ ((row & 7) << 4)));
}

__device__ __forceinline__ f16x8 cvt8(const float* q) {
    float4 u0 = *(const float4*)q;
    float4 u1 = *(const float4*)(q + 4);
    f16x8 r;
    r[0] = (f16)u0.x; r[1] = (f16)u0.y; r[2] = (f16)u0.z; r[3] = (f16)u0.w;
    r[4] = (f16)u1.x; r[5] = (f16)u1.y; r[6] = (f16)u1.z; r[7] = (f16)u1.w;
    return r;
}

// Pack 6 sections of B-fragments (each 16sk x 32nsub x 64lane f16x8):
// sections 0..2: forward W1..W3  (N=out row n, K=in k):  elem W[n*DD + k+j]
// sections 3..5: backward W1..W3 transposed (K=out, N=in): elem W[(k+j)*DD + n]
__global__ void prep_w(const float* __restrict__ W1, const float* __restrict__ W2,
                       const float* __restrict__ W3, f16* __restrict__ wp) {
    int tid = blockIdx.x * 256 + threadIdx.x;
    if (tid >= 6 * 16 * 32 * 64) return;
    int lane = tid & 63;
    int frag = tid >> 6;
    int nsub = frag & 31;
    int sk   = (frag >> 5) & 15;
    int l    = frag >> 9;          // 0..5
    int lw   = l - (l >= 3 ? 3 : 0);
    const float* W = (lw == 0) ? W1 : (lw == 1) ? W2 : W3;
    int n = nsub * 16 + (lane & 15);
    int k = sk * 32 + (lane >> 4) * 8;
    f16x8 o;
    if (l < 3) {
        const float* p = W + (size_t)n * DD + k;
        #pragma unroll
        for (int j = 0; j < 8; ++j) o[j] = (f16)p[j];
    } else {
        const float* p = W + (size_t)k * DD + n;
        #pragma unroll
        for (int j = 0; j < 8; ++j) o[j] = (f16)p[j * DD];
    }
    ((f16x8*)wp)[tid] = o;
}

#define MFMA1(A, B, C) __builtin_amdgcn_mfma_f32_16x16x32_f16(A, B, C, 0, 0, 0)

// one k-slice: 2 A-rows (M=32) x 2 B frags (wave owns 32 N-cols) -> 4 MFMA
#define MFMA_SK2(TB, skc, Q0, Q1)                                              \
    { f16x8 aA = ldA8(TB, l15,      (skc) * 64 + g16 * 16);                    \
      f16x8 aB = ldA8(TB, 16 + l15, (skc) * 64 + g16 * 16);                    \
      acc[0][0] = MFMA1(aA, Q0, acc[0][0]); acc[0][1] = MFMA1(aA, Q1, acc[0][1]); \
      acc[1][0] = MFMA1(aB, Q0, acc[1][0]); acc[1][1] = MFMA1(aB, Q1, acc[1][1]); }

// packed B load (PREP) for section pointer wS (pre-offset by wave+lane)
#define LOADB_P(wS, Q0, Q1, skc)                                               \
    { const f16x8* p_ = (wS) + ((size_t)(skc) << 11);                          \
      Q0 = p_[0]; Q1 = p_[64]; }

// 16 waves (1024 thr): 4 waves/SIMD for latency hiding (rounds 7-10 lesson:
// 2 waves/SIMD leaves every pipe <50% on dependency stalls; 512-thr blocks
// never co-schedule 2/CU, so put the waves inside ONE block).
template<bool PREP>
__global__ __launch_bounds__(1024) void mlp_fused(
    const float* __restrict__ tx,
    const float* __restrict__ W0, const float* __restrict__ b0v,
    const float* __restrict__ W1, const float* __restrict__ b1v,
    const float* __restrict__ W2, const float* __restrict__ b2v,
    const float* __restrict__ W3, const float* __restrict__ b3v,
    const float* __restrict__ W4, const float* __restrict__ b4v,
    const f16* __restrict__ wp, float* __restrict__ out)
{
    // Reverse-mode: forward stores h1,h2,h3 (tiles 0..2); G holds gz_l.
    __shared__ __align__(16) short abuf_s[4 * 32 * DD];  // 128 KB
    __shared__ float txb[TM * 3];
    __shared__ float pbuf[16][32];                       // p partials per wave
    char* ab = (char*)abuf_s;
    char* G  = ab + 3 * 32768;

    const int tid  = threadIdx.x;
    const int lane = tid & 63;
    const int wv   = tid >> 6;   // 0..15, owns cols [wv*32, wv*32+32)
    const int g16  = lane >> 4;
    const int l15  = lane & 15;
    const long s0  = (long)blockIdx.x * TM;

    if (tid < TM * 3) txb[tid] = tx[s0 * 3 + tid];
    __syncthreads();

    // ---- layer 0: h1 = sp20(W0 x + b0)  (K=3, fp32 VALU) -> tile 0
    // 1024 threads, 512 neurons: thread handles 16 of the 32 samples.
    {
        int n  = tid & 511;
        int sb = (tid >> 9) * 16;
        float w0 = W0[n * 3 + 0], w1 = W0[n * 3 + 1], w2 = W0[n * 3 + 2], bb = b0v[n];
        #pragma unroll 4
        for (int si = 0; si < 16; ++si) {
            int s = sb + si;
            float z  = fmaf(w0, txb[s * 3], fmaf(w1, txb[s * 3 + 1], fmaf(w2, txb[s * 3 + 2], bb)));
            float aa = fabsf(z);
            float e  = __expf(-20.f * aa);
            float dd = 1.f + e;
            float h  = fmaxf(z, 0.f) + __logf(dd) * 0.05f;
            stA(ab, s, n * 2, h);
        }
    }
    __syncthreads();

    // ---- forward: h_{i+2} = sp20(W_{i+1} h_{i+1} + b)  (i=0,1); i=2 -> gz4 + p
    for (int i = 0; i < 3; ++i) {
        const float* Wl = (i == 0) ? W1 : (i == 1) ? W2 : W3;
        const float* bl = (i == 0) ? b1v : (i == 1) ? b2v : b3v;
        const f16x8* wS = (const f16x8*)wp + (size_t)i * (16 * 32 * 64)
                        + (size_t)(wv * 2) * 64 + lane;
        const char* Tin = ab + i * 32768;

        f32x4 acc[2][2];
        acc[0][0] = f32x4{0.f,0.f,0.f,0.f}; acc[0][1] = f32x4{0.f,0.f,0.f,0.f};
        acc[1][0] = f32x4{0.f,0.f,0.f,0.f}; acc[1][1] = f32x4{0.f,0.f,0.f,0.f};

        #pragma unroll 2
        for (int sk = 0; sk < 16; ++sk) {
            f16x8 b0, b1;
            if constexpr (PREP) {
                LOADB_P(wS, b0, b1, sk)
            } else {
                const float* q = Wl + (size_t)(wv * 32 + l15) * DD + sk * 32 + g16 * 8;
                b0 = cvt8(q);
                b1 = cvt8(q + 16 * DD);
            }
            MFMA_SK2(Tin, sk, b0, b1)
        }

        if (i < 2) {
            char* Tout = ab + (i + 1) * 32768;
            #pragma unroll
            for (int m = 0; m < 2; ++m)
                #pragma unroll
                for (int n = 0; n < 2; ++n) {
                    float bias = bl[wv * 32 + n * 16 + l15];
                    int   cb   = (wv * 32 + n * 16 + l15) * 2;
                    #pragma unroll
                    for (int r = 0; r < 4; ++r) {
                        int row = m * 16 + g16 * 4 + r;
                        float z  = acc[m][n][r] + bias;
                        float aa = fabsf(z);
                        float e  = __expf(-20.f * aa);
                        float dd = 1.f + e;
                        float h  = fmaxf(z, 0.f) + __logf(dd) * 0.05f;
                        stA(Tout, row, cb, h);
                    }
                }
        } else {
            // z4 -> gz4 = W4[0][col]*sigmoid(20 z4) -> G ; p-partials -> pbuf
            #pragma unroll
            for (int m = 0; m < 2; ++m)
                #pragma unroll
                for (int r = 0; r < 4; ++r) {
                    int row = m * 16 + g16 * 4 + r;
                    float pp = 0.f;
                    #pragma unroll
                    for (int n = 0; n < 2; ++n) {
                        int col = wv * 32 + n * 16 + l15;
                        float z  = acc[m][n][r] + bl[col];
                        float aa = fabsf(z);
                        float e  = __expf(-20.f * aa);
                        float dd = 1.f + e;
                        float rd = __builtin_amdgcn_rcpf(dd);
                        float h4 = fmaxf(z, 0.f) + __logf(dd) * 0.05f;
                        float sg = (z > 0.f ? 1.f : e) * rd;
                        pp = fmaf(W4[DD + col], h4, pp);
                        stA(G, row, col * 2, W4[col] * sg);
                    }
                    pp += __shfl_xor(pp, 1);
                    pp += __shfl_xor(pp, 2);
                    pp += __shfl_xor(pp, 4);
                    pp += __shfl_xor(pp, 8);
                    if (l15 == 0) pbuf[wv][row] = pp;
                }
        }
        __syncthreads();
    }

    // ---- backward: gz_{3-b} = (gz_{4-b} W_{3-b}^T) * sigma(h_{3-b}), in-place in G
    for (int b = 0; b < 3; ++b) {
        const f16x8* wS = (const f16x8*)wp + (size_t)(5 - b) * (16 * 32 * 64)
                        + (size_t)(wv * 2) * 64 + lane;
        const float* Wb = (b == 0) ? W3 : (b == 1) ? W2 : W1;
        const char* Th = ab + (2 - b) * 32768;  // h_{3-b}

        f32x4 acc[2][2];
        acc[0][0] = f32x4{0.f,0.f,0.f,0.f}; acc[0][1] = f32x4{0.f,0.f,0.f,0.f};
        acc[1][0] = f32x4{0.f,0.f,0.f,0.f}; acc[1][1] = f32x4{0.f,0.f,0.f,0.f};

        #pragma unroll 2
        for (int sk = 0; sk < 16; ++sk) {
            f16x8 b0, b1;
            if constexpr (PREP) {
                LOADB_P(wS, b0, b1, sk)
            } else {
                const float* q = Wb + (size_t)(sk * 32 + g16 * 8) * DD + wv * 32 + l15;
                f16x8 t0, t1;
                #pragma unroll
                for (int j = 0; j < 8; ++j) {
                    t0[j] = (f16)q[j * DD];
                    t1[j] = (f16)q[j * DD + 16];
                }
                b0 = t0; b1 = t1;
            }
            MFMA_SK2(G, sk, b0, b1)
        }
        __syncthreads();  // all waves done reading G before overwrite

        #pragma unroll
        for (int m = 0; m < 2; ++m)
            #pragma unroll
            for (int n = 0; n < 2; ++n) {
                int cb = (wv * 32 + n * 16 + l15) * 2;
                #pragma unroll
                for (int r = 0; r < 4; ++r) {
                    int row = m * 16 + g16 * 4 + r;
                    float h  = ldh(Th, row, cb);
                    float sg = 1.f - __expf(-20.f * h);  // sigmoid(20z) via h
                    stA(G, row, cb, sg * acc[m][n][r]);
                }
            }
        __syncthreads();
    }

    // ---- final: u = (dy, -dx) from gz1 . W0 cols; p from pbuf
    {
        const int kb = lane * 8;
        float wyr[8], wxr[8];
        #pragma unroll
        for (int j = 0; j < 8; ++j) {
            wyr[j] = W0[(kb + j) * 3 + 2];
            wxr[j] = W0[(kb + j) * 3 + 1];
        }
        float bp = b4v[1];
        #pragma unroll
        for (int ii = 0; ii < 2; ++ii) {
            int s = wv * 2 + ii;
            f16x8 gg = ldA8(G, s, lane * 16);
            float dy = 0.f, dx = 0.f;
            #pragma unroll
            for (int j = 0; j < 8; ++j) {
                dy = fmaf(wyr[j], (float)gg[j], dy);
                dx = fmaf(wxr[j], (float)gg[j], dx);
            }
            #pragma unroll
            for (int mk = 1; mk < 64; mk <<= 1) {
                dy += __shfl_xor(dy, mk);
                dx += __shfl_xor(dx, mk);
            }
            if (lane == 0) {
                float ps = bp;
                #pragma unroll
                for (int w = 0; w < 16; ++w) ps += pbuf[w][s];
                float* o = out + (s0 + s) * 3;
                o[0] = dy;        // ds/dy
                o[1] = -dx;       // -ds/dx
                o[2] = ps;        // pressure
            }
        }
    }
}

extern "C" void kernel_launch(void* const* d_in, const int* in_sizes, int n_in,
                              void* d_out, int out_size, void* d_ws, size_t ws_size,
                              hipStream_t stream) {
    const float* tx = (const float*)d_in[0];
    const float* W0 = (const float*)d_in[1]; const float* b0 = (const float*)d_in[2];
    const float* W1 = (const float*)d_in[3]; const float* b1 = (const float*)d_in[4];
    const float* W2 = (const float*)d_in[5]; const float* b2 = (const float*)d_in[6];
    const float* W3 = (const float*)d_in[7]; const float* b3 = (const float*)d_in[8];
    const float* W4 = (const float*)d_in[9]; const float* b4 = (const float*)d_in[10];
    float* out = (float*)d_out;

    const size_t need = (size_t)6 * 512 * 512 * sizeof(f16);  // 3 MB: fwd + bwd packs
    if (ws_size >= need) {
        f16* wp = (f16*)d_ws;
        prep_w<<<(6 * 16 * 32 * 64 + 255) / 256, 256, 0, stream>>>(W1, W2, W3, wp);
        mlp_fused<true><<<NBLK, 1024, 0, stream>>>(tx, W0, b0, W1, b1, W2, b2, W3, b3, W4, b4, wp, out);
    } else {
        mlp_fused<false><<<NBLK, 1024, 0, stream>>>(tx, W0, b0, W1, b1, W2, b2, W3, b3, W4, b4, nullptr, out);
    }
}